// Round 8
// baseline (220.987 us; speedup 1.0000x reference)
//
#include <hip/hip_runtime.h>

#define DD 1024   // hidden size
#define MM 256    // random features
#define NN 16384  // hidden states
#define KK 8192   // weight rows

typedef float f32x4 __attribute__((ext_vector_type(4)));
typedef unsigned int u32x4 __attribute__((ext_vector_type(4)));
typedef __bf16 bf16x8 __attribute__((ext_vector_type(8)));
typedef unsigned short u16;
typedef unsigned int u32;

static __device__ __forceinline__ u16 f2bf(float f) {
    u32 u = __builtin_bit_cast(u32, f);
    u32 r = u + 0x7fffu + ((u >> 16) & 1u);
    return (u16)(r >> 16);
}
static __device__ __forceinline__ float bf2f(u16 h) {
    u32 u = ((u32)h) << 16;
    return __builtin_bit_cast(float, u);
}

static __device__ __forceinline__ void gload_lds16(const void* g, void* l) {
    __builtin_amdgcn_global_load_lds(
        (const __attribute__((address_space(1))) u32*)g,
        (__attribute__((address_space(3))) u32*)l, 16, 0, 0);
}

static __device__ __forceinline__ bf16x8 ldfrag(const u16* p) {
    return __builtin_bit_cast(bf16x8, *(const u32x4*)p);
}

#define MFMA16(a, b, c) __builtin_amdgcn_mfma_f32_16x16x32_bf16((a), (b), (c), 0, 0, 0)

// ---------------------------------------------------------------------------
// Kernel 1: omega fp32 -> (hi, lo) bf16 split   [R5 verbatim]
// ---------------------------------------------------------------------------
__global__ void k_conv(const float* __restrict__ om, u16* __restrict__ oh,
                       u16* __restrict__ ol) {
    int i = (blockIdx.x * blockDim.x + threadIdx.x) * 4;
    f32x4 x = *(const f32x4*)(om + i);
    ushort4 h, l;
    u16 t;
    t = f2bf(x.x); h.x = t; l.x = f2bf(x.x - bf2f(t));
    t = f2bf(x.y); h.y = t; l.y = f2bf(x.y - bf2f(t));
    t = f2bf(x.z); h.z = t; l.z = f2bf(x.z - bf2f(t));
    t = f2bf(x.w); h.w = t; l.w = f2bf(x.w - bf2f(t));
    *(ushort4*)(oh + i) = h;
    *(ushort4*)(ol + i) = l;
}

// ---------------------------------------------------------------------------
// Kernel 2: Stage A — proj = X @ Omega^T, split-bf16 (3 MFMA products).
// Barrier-free wave-local COUNTED-VMCNT pipeline (T4):
//   - each wave stages its own 64 Omega rows (hi+lo) into private LDS,
//     1 step ahead (L2-hot, ~300cy latency)
//   - X loaded direct-to-fragment registers 2 steps ahead (HBM ~900cy);
//     ping-pong buffers: consume-convert THEN reload same buffer -> static idx
//   - per-step issue order [stageO(k+1)=8, loadX(k+2)=4] => steady-state wait
//     is s_waitcnt vmcnt(4) (X_{k+2} stays in flight), vmcnt(0) only at the
//     last step. lgkmcnt(0) guards the WAR on the single Omega buffer.
// NO __syncthreads in the K-loop. 32 rows/block, 768 blocks, 32.5KB LDS,
// 3 blocks/CU.
// ---------------------------------------------------------------------------
__global__ __launch_bounds__(256, 3)
void k_stageA(const float* __restrict__ Hs, const float* __restrict__ Ws,
              const u16* __restrict__ Oh, const u16* __restrict__ Ol,
              u16* __restrict__ phiH, u16* __restrict__ phiW,
              float* __restrict__ emH, float* __restrict__ emW)
{
    __shared__ alignas(16) u16 BhS[4][64 * 32];   // per-wave private regions
    __shared__ alignas(16) u16 BlS[4][64 * 32];
    __shared__ float redmax[4][32];

    const int tid  = threadIdx.x;
    const int lane = tid & 63;
    const int wid  = tid >> 6;
    const int r16  = lane & 15;
    const int h8   = (lane >> 4) << 3;

    const float* __restrict__ X;
    u16* __restrict__ phi;
    float* __restrict__ em;
    int row0;
    if (blockIdx.x < NN / 32) {
        X = Hs; phi = phiH; em = emH; row0 = blockIdx.x * 32;
    } else {
        X = Ws; phi = phiW; em = emW; row0 = (blockIdx.x - NN / 32) * 32;
    }

    f32x4 acc[2][4];
#pragma unroll
    for (int m = 0; m < 2; ++m)
#pragma unroll
        for (int n = 0; n < 4; ++n) acc[m][n] = f32x4{0.f, 0.f, 0.f, 0.f};

    u16* const mybh = &BhS[wid][0];
    u16* const mybl = &BlS[wid][0];

    // fragment read offsets within own region (u16 units); rows local 0..63
    int boffs[4];
#pragma unroll
    for (int n = 0; n < 4; ++n) {
        int rl = n * 16 + r16;
        boffs[n] = rl * 32 + (h8 ^ (((rl >> 1) & 3) << 3));
    }

    // staging sources: inst s covers local rows s*16+(lane>>2), col-seg
    // (lane&3)*8, source column pre-swizzled so linear LDS dest + swizzled
    // read match.
    const u16* srch[4];
    const u16* srcl[4];
#pragma unroll
    for (int s = 0; s < 4; ++s) {
        int rl  = s * 16 + (lane >> 2);
        int col = ((lane & 3) << 3) ^ (((rl >> 1) & 3) << 3);
        srch[s] = Oh + (long)(wid * 64 + rl) * DD + col;
        srcl[s] = Ol + (long)(wid * 64 + rl) * DD + col;
    }

    // A-operand global base pointers (frag: row = row0+m*16+r16, k = h8+j)
    const float* xb[2];
#pragma unroll
    for (int m = 0; m < 2; ++m)
        xb[m] = X + (long)(row0 + m * 16 + r16) * DD + h8;

    u32x4 xrA[2][2], xrB[2][2];

    auto stageO = [&](int k0) {
#pragma unroll
        for (int s = 0; s < 4; ++s) {
            gload_lds16(srch[s] + k0, mybh + s * 512);
            gload_lds16(srcl[s] + k0, mybl + s * 512);
        }
    };
    auto loadX = [&](int k0, u32x4 (&xr)[2][2]) {
#pragma unroll
        for (int m = 0; m < 2; ++m) {
            xr[m][0] = *(const u32x4*)(xb[m] + k0);
            xr[m][1] = *(const u32x4*)(xb[m] + k0 + 4);
        }
    };
    // step: consumes xr (X_k) + own-LDS Omega_k; issues stageO(k_stage) and
    // loadX(k_load) into the SAME xr buffer (freed by the convert).
    auto step = [&](u32x4 (&xr)[2][2], int k_stage, int k_load, bool last) {
        // wait: X_k + Omega_k complete. Steady state leaves X_{k+1} (4 ops)
        // in flight; last step has nothing younger -> full drain.
        if (last) asm volatile("s_waitcnt vmcnt(0)" ::: "memory");
        else      asm volatile("s_waitcnt vmcnt(4)" ::: "memory");
        bf16x8 fbh[4], fbl[4];
#pragma unroll
        for (int n = 0; n < 4; ++n) {
            fbh[n] = ldfrag(mybh + boffs[n]);
            fbl[n] = ldfrag(mybl + boffs[n]);
        }
        // convert current X regs -> hi/lo fragments (frees xr)
        bf16x8 fah[2], fal[2];
#pragma unroll
        for (int m = 0; m < 2; ++m) {
            f32x4 a = __builtin_bit_cast(f32x4, xr[m][0]);
            f32x4 b = __builtin_bit_cast(f32x4, xr[m][1]);
            const float e[8] = {a[0], a[1], a[2], a[3], b[0], b[1], b[2], b[3]};
            u32x4 ph, pl;
#pragma unroll
            for (int j = 0; j < 4; ++j) {
                u16 h0 = f2bf(e[2 * j]);
                u16 h1 = f2bf(e[2 * j + 1]);
                u16 l0 = f2bf(e[2 * j] - bf2f(h0));
                u16 l1 = f2bf(e[2 * j + 1] - bf2f(h1));
                ph[j] = (u32)h0 | ((u32)h1 << 16);
                pl[j] = (u32)l0 | ((u32)l1 << 16);
            }
            fah[m] = __builtin_bit_cast(bf16x8, ph);
            fal[m] = __builtin_bit_cast(bf16x8, pl);
        }
        // ds_reads retired -> safe to overwrite own region with next tile
        asm volatile("s_waitcnt lgkmcnt(0)" ::: "memory");
        if (k_stage < DD) stageO(k_stage);
        if (k_load < DD) loadX(k_load, xr);
#pragma unroll
        for (int m = 0; m < 2; ++m)
#pragma unroll
            for (int n = 0; n < 4; ++n) {
                acc[m][n] = MFMA16(fah[m], fbh[n], acc[m][n]);
                acc[m][n] = MFMA16(fah[m], fbl[n], acc[m][n]);
                acc[m][n] = MFMA16(fal[m], fbh[n], acc[m][n]);
            }
    };

    // prologue: X0, Omega0, X1 in flight  (FIFO: [X0(4), O0(8), X1(4)])
    loadX(0, xrA);
    stageO(0);
    loadX(32, xrB);

    // steps 0..29 (2-unrolled ping-pong), then peeled steps 30, 31
    for (int ks = 0; ks < 30; ks += 2) {
        step(xrA, (ks + 1) * 32, (ks + 2) * 32, false);
        step(xrB, (ks + 2) * 32, (ks + 3) * 32, false);
    }
    step(xrA, 31 * 32, 32 * 32, false);   // step 30: stages Omega_31, no X
    step(xrB, 32 * 32, 33 * 32, true);    // step 31: drain only

    // row max: lane-local over n, reduce across 16 lanes sharing a row,
    // then across the 4 waves' column slices (barriers — end only)
#pragma unroll
    for (int m = 0; m < 2; ++m)
#pragma unroll
        for (int i = 0; i < 4; ++i) {
            float v = fmaxf(fmaxf(acc[m][0][i], acc[m][1][i]),
                            fmaxf(acc[m][2][i], acc[m][3][i]));
            v = fmaxf(v, __shfl_xor(v, 1));
            v = fmaxf(v, __shfl_xor(v, 2));
            v = fmaxf(v, __shfl_xor(v, 4));
            v = fmaxf(v, __shfl_xor(v, 8));
            if (r16 == 0) redmax[wid][m * 16 + ((lane >> 4) << 2) + i] = v;
        }
    __syncthreads();
    if (tid < 32) {
        float fm = fmaxf(fmaxf(redmax[0][tid], redmax[1][tid]),
                         fmaxf(redmax[2][tid], redmax[3][tid]));
        // em = exp(-clamp(max)) so stage B epilogue needs no log/exp
        em[row0 + tid] = __expf(fminf(fmaxf(-fm, -87.f), 87.f));
    }
#pragma unroll
    for (int m = 0; m < 2; ++m)
#pragma unroll
        for (int i = 0; i < 4; ++i) {
            const int rl = m * 16 + ((lane >> 4) << 2) + i;
            const float fm = fmaxf(fmaxf(redmax[0][rl], redmax[1][rl]),
                                   fmaxf(redmax[2][rl], redmax[3][rl]));
#pragma unroll
            for (int n = 0; n < 4; ++n) {
                float p   = acc[m][n][i];
                float ph_ = (__expf(p - fm) + 1e-6f) * 0.0625f;
                phi[(long)(row0 + rl) * MM + wid * 64 + n * 16 + r16] = f2bf(ph_);
            }
        }
}

// ---------------------------------------------------------------------------
// Kernel 3: Stage B — rf = phi_h @ phi_w^T (K=256), epilogue
//   out = rf' / (rf' + eh*ew),  rf' = rf + 1e-10   (no log/exp/div!)
// 128x128 tile, 4 waves (64x64 each), BK=64, non-temporal output stores.
// [R5 verbatim — proven component of the 196us run]
// ---------------------------------------------------------------------------
__global__ __launch_bounds__(256, 3)
void k_stageB(const u16* __restrict__ PH, const u16* __restrict__ PW,
              const float* __restrict__ EH, const float* __restrict__ EW,
              float* __restrict__ out)
{
    __shared__ alignas(16) u16 As[128 * 64];
    __shared__ alignas(16) u16 Bs[128 * 64];

    const int tid  = threadIdx.x;
    const int lane = tid & 63;
    const int wid  = tid >> 6;
    const int bm   = blockIdx.x >> 6;   // 0..127
    const int bn   = blockIdx.x & 63;   // 0..63
    const int row0 = bm * 128, col0 = bn * 128;
    const int wr   = wid >> 1, wc = wid & 1;
    const int r16  = lane & 15;
    const int h8   = (lane >> 4) << 3;

    f32x4 acc[4][4];
#pragma unroll
    for (int m = 0; m < 4; ++m)
#pragma unroll
        for (int n = 0; n < 4; ++n) acc[m][n] = f32x4{0.f, 0.f, 0.f, 0.f};

    // fragment offsets (u16 units) for both 32-wide k-slices; 128B rows,
    // byte swizzle = ((row&7)<<4)
    int aoffs[2][4], boffs[2][4];
#pragma unroll
    for (int sl = 0; sl < 2; ++sl) {
#pragma unroll
        for (int m = 0; m < 4; ++m) {
            int row = wr * 64 + m * 16 + r16;
            aoffs[sl][m] = row * 64 + (((((sl * 32 + h8) << 1)) ^ ((row & 7) << 4)) >> 1);
        }
#pragma unroll
        for (int n = 0; n < 4; ++n) {
            int row = wc * 64 + n * 16 + r16;
            boffs[sl][n] = row * 64 + (((((sl * 32 + h8) << 1)) ^ ((row & 7) << 4)) >> 1);
        }
    }

    for (int ks = 0; ks < 4; ++ks) {
        const int k0 = ks * 64;
#pragma unroll
        for (int s = 0; s < 4; ++s) {
            const int c    = s * 256 + tid;
            const int row  = c >> 3;
            const int cbl  = ((c & 7) << 4) ^ ((row & 7) << 4);
            const int scol = k0 + (cbl >> 1);
            gload_lds16(PH + (long)(row0 + row) * MM + scol, As + (s * 256 + wid * 64) * 8);
            gload_lds16(PW + (long)(col0 + row) * MM + scol, Bs + (s * 256 + wid * 64) * 8);
        }
        __syncthreads();
#pragma unroll
        for (int sl = 0; sl < 2; ++sl) {
            bf16x8 fa[4], fb[4];
#pragma unroll
            for (int m = 0; m < 4; ++m) fa[m] = ldfrag(As + aoffs[sl][m]);
#pragma unroll
            for (int n = 0; n < 4; ++n) fb[n] = ldfrag(Bs + boffs[sl][n]);
#pragma unroll
            for (int m = 0; m < 4; ++m)
#pragma unroll
                for (int n = 0; n < 4; ++n)
                    acc[m][n] = MFMA16(fa[m], fb[n], acc[m][n]);
        }
        __syncthreads();
    }

    // epilogue: out = rf' / (rf' + eh*ew)
    float ew_[4];
#pragma unroll
    for (int n = 0; n < 4; ++n) ew_[n] = EW[col0 + wc * 64 + n * 16 + r16];

#pragma unroll
    for (int m = 0; m < 4; ++m) {
#pragma unroll
        for (int i = 0; i < 4; ++i) {
            const int row = row0 + wr * 64 + m * 16 + ((lane >> 4) << 2) + i;
            const float eh = EH[row];
#pragma unroll
            for (int n = 0; n < 4; ++n) {
                float rf = acc[m][n][i] + 1e-10f;
                float t  = eh * ew_[n];
                float o  = rf * __builtin_amdgcn_rcpf(rf + t);
                __builtin_nontemporal_store(
                    o, &out[(long)row * KK + col0 + wc * 64 + n * 16 + r16]);
            }
        }
    }
}

// ---------------------------------------------------------------------------
extern "C" void kernel_launch(void* const* d_in, const int* in_sizes, int n_in,
                              void* d_out, int out_size, void* d_ws, size_t ws_size,
                              hipStream_t stream) {
    (void)in_sizes; (void)n_in; (void)out_size; (void)ws_size;
    const float* H  = (const float*)d_in[0];
    const float* W  = (const float*)d_in[1];
    const float* Om = (const float*)d_in[2];
    float* out = (float*)d_out;

    char* ws   = (char*)d_ws;
    u16*  phiH = (u16*)ws;                                       // 8 MB
    u16*  phiW = (u16*)(ws + (size_t)NN * MM * 2);               // 4 MB
    float* emh = (float*)(ws + (size_t)(NN + KK) * MM * 2);      // 64 KB
    float* emw = emh + NN;                                       // 32 KB
    u16*  oh   = (u16*)(emw + KK);                               // 512 KB
    u16*  ol   = oh + MM * DD;                                   // 512 KB

    k_conv<<<(MM * DD) / 1024, 256, 0, stream>>>(Om, oh, ol);
    k_stageA<<<(NN + KK) / 32, 256, 0, stream>>>(H, W, oh, ol, phiH, phiW, emh, emw);
    k_stageB<<<(NN / 128) * (KK / 128), 256, 0, stream>>>(phiH, phiW, emh, emw, out);
}

// Round 9
// 182.334 us; speedup vs baseline: 1.2120x; 1.2120x over previous
//
#include <hip/hip_runtime.h>

#define DD 1024   // hidden size
#define MM 256    // random features
#define NN 16384  // hidden states
#define KK 8192   // weight rows

typedef float f32x4 __attribute__((ext_vector_type(4)));
typedef unsigned int u32x4 __attribute__((ext_vector_type(4)));
typedef unsigned int u32x2 __attribute__((ext_vector_type(2)));
typedef __bf16 bf16x8 __attribute__((ext_vector_type(8)));
typedef unsigned short u16;
typedef unsigned int u32;

static __device__ __forceinline__ u16 f2bf(float f) {
    u32 u = __builtin_bit_cast(u32, f);
    u32 r = u + 0x7fffu + ((u >> 16) & 1u);
    return (u16)(r >> 16);
}
static __device__ __forceinline__ float bf2f(u16 h) {
    u32 u = ((u32)h) << 16;
    return __builtin_bit_cast(float, u);
}

static __device__ __forceinline__ void gload_lds16(const void* g, void* l) {
    __builtin_amdgcn_global_load_lds(
        (const __attribute__((address_space(1))) u32*)g,
        (__attribute__((address_space(3))) u32*)l, 16, 0, 0);
}

static __device__ __forceinline__ bf16x8 ldfrag(const u16* p) {
    return __builtin_bit_cast(bf16x8, *(const u32x4*)p);
}

#define MFMA16(a, b, c) __builtin_amdgcn_mfma_f32_16x16x32_bf16((a), (b), (c), 0, 0, 0)

// ---------------------------------------------------------------------------
// Kernel 1: omega fp32 -> (hi, lo) bf16 split   [R5 verbatim]
// ---------------------------------------------------------------------------
__global__ void k_conv(const float* __restrict__ om, u16* __restrict__ oh,
                       u16* __restrict__ ol) {
    int i = (blockIdx.x * blockDim.x + threadIdx.x) * 4;
    f32x4 x = *(const f32x4*)(om + i);
    ushort4 h, l;
    u16 t;
    t = f2bf(x.x); h.x = t; l.x = f2bf(x.x - bf2f(t));
    t = f2bf(x.y); h.y = t; l.y = f2bf(x.y - bf2f(t));
    t = f2bf(x.z); h.z = t; l.z = f2bf(x.z - bf2f(t));
    t = f2bf(x.w); h.w = t; l.w = f2bf(x.w - bf2f(t));
    *(ushort4*)(oh + i) = h;
    *(ushort4*)(ol + i) = l;
}

// ---------------------------------------------------------------------------
// Kernel 2: merged Stage A (H and W in one grid) — proj = X @ Omega^T with
// split-bf16 (3 MFMA products). Block = 32 rows x all 256 cols -> rowmax
// block-local -> phi (bf16) + em = exp(clamp(-rowmax, +-87)) (f32).
// [R5 verbatim — proven fastest stage A; R6/R7/R8 restructures all regressed]
// ---------------------------------------------------------------------------
__global__ __launch_bounds__(256, 4)
void k_stageA(const float* __restrict__ Hs, const float* __restrict__ Ws,
              const u16* __restrict__ Oh, const u16* __restrict__ Ol,
              u16* __restrict__ phiH, u16* __restrict__ phiW,
              float* __restrict__ emH, float* __restrict__ emW)
{
    __shared__ alignas(16) u16 Ah[32 * 32];
    __shared__ alignas(16) u16 Al[32 * 32];
    __shared__ alignas(16) u16 Bh[256 * 32];
    __shared__ alignas(16) u16 Bl[256 * 32];
    __shared__ float redmax[4][32];

    const int tid  = threadIdx.x;
    const int lane = tid & 63;
    const int wid  = tid >> 6;

    const float* __restrict__ X;
    u16* __restrict__ phi;
    float* __restrict__ em;
    int row0;
    if (blockIdx.x < NN / 32) {
        X = Hs; phi = phiH; em = emH; row0 = blockIdx.x * 32;
    } else {
        X = Ws; phi = phiW; em = emW; row0 = (blockIdx.x - NN / 32) * 32;
    }

    f32x4 acc[2][4];
#pragma unroll
    for (int m = 0; m < 2; ++m)
#pragma unroll
        for (int n = 0; n < 4; ++n) acc[m][n] = f32x4{0.f, 0.f, 0.f, 0.f};

    // A staging: thread loads float4 (row arow, fp32 cols acol..acol+3)
    const int arow = tid >> 3;           // 0..31
    const int acol = (tid & 7) * 4;      // 0,4,..,28
    const float* __restrict__ xrow = X + (long)(row0 + arow) * DD;
    // u16-unit LDS index; XOR swizzle on 8-u16 (16B) blocks
    const int a_idx = arow * 32 + (acol ^ (((arow >> 1) & 3) << 3));

    const int r16 = lane & 15;
    const int h8  = (lane >> 4) << 3;
    int aoffs[2], boffs[4];
#pragma unroll
    for (int m = 0; m < 2; ++m) {
        int row = m * 16 + r16;
        aoffs[m] = row * 32 + (h8 ^ (((row >> 1) & 3) << 3));
    }
#pragma unroll
    for (int n = 0; n < 4; ++n) {
        int row = wid * 64 + n * 16 + r16;
        boffs[n] = row * 32 + (h8 ^ (((row >> 1) & 3) << 3));
    }

    for (int ks = 0; ks < DD / 32; ++ks) {
        const int k0 = ks * 32;
        // Omega tile hi/lo via async global->LDS (width 16), pre-swizzled src
#pragma unroll
        for (int s = 0; s < 4; ++s) {
            const int c    = s * 256 + tid;
            const int brow = c >> 2;
            const int scol = k0 + (((c & 3) << 3) ^ (((brow >> 1) & 3) << 3));
            gload_lds16(Oh + brow * DD + scol, Bh + (s * 256 + wid * 64) * 8);
            gload_lds16(Ol + brow * DD + scol, Bl + (s * 256 + wid * 64) * 8);
        }
        // X tile: load fp32x4, split to hi/lo bf16, write LDS (8B)
        f32x4 x = *(const f32x4*)(xrow + k0 + acol);
        u32x2 ph, pl;
#pragma unroll
        for (int j = 0; j < 2; ++j) {
            u16 h0 = f2bf(x[2 * j]);
            u16 h1 = f2bf(x[2 * j + 1]);
            u16 l0 = f2bf(x[2 * j] - bf2f(h0));
            u16 l1 = f2bf(x[2 * j + 1] - bf2f(h1));
            ph[j] = (u32)h0 | ((u32)h1 << 16);
            pl[j] = (u32)l0 | ((u32)l1 << 16);
        }
        *(u32x2*)(Ah + a_idx) = ph;
        *(u32x2*)(Al + a_idx) = pl;
        __syncthreads();

        bf16x8 fah[2], fal[2], fbh[4], fbl[4];
#pragma unroll
        for (int m = 0; m < 2; ++m) {
            fah[m] = ldfrag(Ah + aoffs[m]);
            fal[m] = ldfrag(Al + aoffs[m]);
        }
#pragma unroll
        for (int n = 0; n < 4; ++n) {
            fbh[n] = ldfrag(Bh + boffs[n]);
            fbl[n] = ldfrag(Bl + boffs[n]);
        }
#pragma unroll
        for (int m = 0; m < 2; ++m)
#pragma unroll
            for (int n = 0; n < 4; ++n) {
                acc[m][n] = MFMA16(fah[m], fbh[n], acc[m][n]);
                acc[m][n] = MFMA16(fah[m], fbl[n], acc[m][n]);
                acc[m][n] = MFMA16(fal[m], fbh[n], acc[m][n]);
            }
        __syncthreads();
    }

    // row max: lane-local over n, then across the 16 lanes sharing a row
#pragma unroll
    for (int m = 0; m < 2; ++m) {
#pragma unroll
        for (int i = 0; i < 4; ++i) {
            float v = fmaxf(fmaxf(acc[m][0][i], acc[m][1][i]),
                            fmaxf(acc[m][2][i], acc[m][3][i]));
            v = fmaxf(v, __shfl_xor(v, 1));
            v = fmaxf(v, __shfl_xor(v, 2));
            v = fmaxf(v, __shfl_xor(v, 4));
            v = fmaxf(v, __shfl_xor(v, 8));
            if (r16 == 0) redmax[wid][m * 16 + ((lane >> 4) << 2) + i] = v;
        }
    }
    __syncthreads();
    if (tid < 32) {
        float fm = fmaxf(fmaxf(redmax[0][tid], redmax[1][tid]),
                         fmaxf(redmax[2][tid], redmax[3][tid]));
        // em = exp(-clamp(max)) so stage B epilogue needs no log/exp
        em[row0 + tid] = __expf(fminf(fmaxf(-fm, -87.f), 87.f));
    }
#pragma unroll
    for (int m = 0; m < 2; ++m) {
#pragma unroll
        for (int i = 0; i < 4; ++i) {
            const int rl = m * 16 + ((lane >> 4) << 2) + i;
            const float fm = fmaxf(fmaxf(redmax[0][rl], redmax[1][rl]),
                                   fmaxf(redmax[2][rl], redmax[3][rl]));
#pragma unroll
            for (int n = 0; n < 4; ++n) {
                float p   = acc[m][n][i];
                float ph_ = (__expf(p - fm) + 1e-6f) * 0.0625f;
                phi[(long)(row0 + rl) * MM + wid * 64 + n * 16 + r16] = f2bf(ph_);
            }
        }
    }
}

// ---------------------------------------------------------------------------
// Kernel 3: Stage B — rf = phi_h @ phi_w^T (K=256), epilogue
//   out = rf' / (rf' + eh*ew),  rf' = rf + 1e-10
// 128x128 tile, 4 waves, BK=64 [K-loop = R5 verbatim].
// NEW: epilogue bounces the f32 output tile through LDS (4 passes of
// 32x128, padded stride 130 -> 2-way-free banks) so each wave issues
// float4/lane stores covering 512B contiguous per 32 lanes -> every 128B
// line completed by ONE instruction. Fixes partial-line (64B) non-temporal
// writes that halve effective HBM write BW.
// ---------------------------------------------------------------------------
__global__ __launch_bounds__(256, 3)
void k_stageB(const u16* __restrict__ PH, const u16* __restrict__ PW,
              const float* __restrict__ EH, const float* __restrict__ EW,
              float* __restrict__ out)
{
    __shared__ alignas(16) u16 smem[2 * 128 * 64];   // As | Bs ; reused as f32 tile
    u16* const As = smem;
    u16* const Bs = smem + 128 * 64;

    const int tid  = threadIdx.x;
    const int lane = tid & 63;
    const int wid  = tid >> 6;
    const int bm   = blockIdx.x >> 6;   // 0..127
    const int bn   = blockIdx.x & 63;   // 0..63
    const int row0 = bm * 128, col0 = bn * 128;
    const int wr   = wid >> 1, wc = wid & 1;
    const int r16  = lane & 15;
    const int h8   = (lane >> 4) << 3;

    f32x4 acc[4][4];
#pragma unroll
    for (int m = 0; m < 4; ++m)
#pragma unroll
        for (int n = 0; n < 4; ++n) acc[m][n] = f32x4{0.f, 0.f, 0.f, 0.f};

    // fragment offsets (u16 units) for both 32-wide k-slices; 128B rows,
    // byte swizzle = ((row&7)<<4)
    int aoffs[2][4], boffs[2][4];
#pragma unroll
    for (int sl = 0; sl < 2; ++sl) {
#pragma unroll
        for (int m = 0; m < 4; ++m) {
            int row = wr * 64 + m * 16 + r16;
            aoffs[sl][m] = row * 64 + (((((sl * 32 + h8) << 1)) ^ ((row & 7) << 4)) >> 1);
        }
#pragma unroll
        for (int n = 0; n < 4; ++n) {
            int row = wc * 64 + n * 16 + r16;
            boffs[sl][n] = row * 64 + (((((sl * 32 + h8) << 1)) ^ ((row & 7) << 4)) >> 1);
        }
    }

    for (int ks = 0; ks < 4; ++ks) {
        const int k0 = ks * 64;
#pragma unroll
        for (int s = 0; s < 4; ++s) {
            const int c    = s * 256 + tid;
            const int row  = c >> 3;
            const int cbl  = ((c & 7) << 4) ^ ((row & 7) << 4);
            const int scol = k0 + (cbl >> 1);
            gload_lds16(PH + (long)(row0 + row) * MM + scol, As + (s * 256 + wid * 64) * 8);
            gload_lds16(PW + (long)(col0 + row) * MM + scol, Bs + (s * 256 + wid * 64) * 8);
        }
        __syncthreads();
#pragma unroll
        for (int sl = 0; sl < 2; ++sl) {
            bf16x8 fa[4], fb[4];
#pragma unroll
            for (int m = 0; m < 4; ++m) fa[m] = ldfrag(As + aoffs[sl][m]);
#pragma unroll
            for (int n = 0; n < 4; ++n) fb[n] = ldfrag(Bs + boffs[sl][n]);
#pragma unroll
            for (int m = 0; m < 4; ++m)
#pragma unroll
                for (int n = 0; n < 4; ++n)
                    acc[m][n] = MFMA16(fa[m], fb[n], acc[m][n]);
        }
        __syncthreads();
    }

    // epilogue: out = rf' / (rf' + eh*ew), via LDS bounce for coalesced stores
    float ew_[4];
#pragma unroll
    for (int n = 0; n < 4; ++n) ew_[n] = EW[col0 + wc * 64 + n * 16 + r16];

    float* const ftile = (float*)smem;   // 32 x 130 (padded) = 16.6 KB
    const int FST = 130;                 // 4*130 % 32 = 8 -> 2-way banks (free)

#pragma unroll
    for (int m = 0; m < 4; ++m) {
        __syncthreads();   // protect previous pass's LDS reads (m=0: K-loop)
#pragma unroll
        for (int i = 0; i < 4; ++i) {
            const int lr   = wr * 16 + ((lane >> 4) << 2) + i;   // 0..31
            const int grow = row0 + wr * 64 + m * 16 + ((lane >> 4) << 2) + i;
            const float eh = EH[grow];
#pragma unroll
            for (int n = 0; n < 4; ++n) {
                float rf = acc[m][n][i] + 1e-10f;
                float t  = eh * ew_[n];
                float o  = rf * __builtin_amdgcn_rcpf(rf + t);
                ftile[lr * FST + wc * 64 + n * 16 + r16] = o;
            }
        }
        __syncthreads();
        // read back + fully-coalesced NT float4 stores (512B / 32 lanes)
#pragma unroll
        for (int p = 0; p < 4; ++p) {
            const int r = p * 8 + (tid >> 5);        // 0..31 local row
            const int c = (tid & 31) * 4;            // 0..124
            f32x4 v = *(const f32x4*)&ftile[r * FST + c];
            const int grow = row0 + m * 16 + ((r >> 4) << 6) + (r & 15);
            __builtin_nontemporal_store(
                v, (f32x4*)(out + (long)grow * KK + col0 + c));
        }
    }
}

// ---------------------------------------------------------------------------
extern "C" void kernel_launch(void* const* d_in, const int* in_sizes, int n_in,
                              void* d_out, int out_size, void* d_ws, size_t ws_size,
                              hipStream_t stream) {
    (void)in_sizes; (void)n_in; (void)out_size; (void)ws_size;
    const float* H  = (const float*)d_in[0];
    const float* W  = (const float*)d_in[1];
    const float* Om = (const float*)d_in[2];
    float* out = (float*)d_out;

    char* ws   = (char*)d_ws;
    u16*  phiH = (u16*)ws;                                       // 8 MB
    u16*  phiW = (u16*)(ws + (size_t)NN * MM * 2);               // 4 MB
    float* emh = (float*)(ws + (size_t)(NN + KK) * MM * 2);      // 64 KB
    float* emw = emh + NN;                                       // 32 KB
    u16*  oh   = (u16*)(emw + KK);                               // 512 KB
    u16*  ol   = oh + MM * DD;                                   // 512 KB

    k_conv<<<(MM * DD) / 1024, 256, 0, stream>>>(Om, oh, ol);
    k_stageA<<<(NN + KK) / 32, 256, 0, stream>>>(H, W, oh, ol, phiH, phiW, emh, emw);
    k_stageB<<<(NN / 128) * (KK / 128), 256, 0, stream>>>(phiH, phiW, emh, emw, out);
}

// Round 10
// 181.278 us; speedup vs baseline: 1.2190x; 1.0058x over previous
//
#include <hip/hip_runtime.h>

#define DD 1024   // hidden size
#define MM 256    // random features
#define NN 16384  // hidden states
#define KK 8192   // weight rows

typedef float f32x4 __attribute__((ext_vector_type(4)));
typedef unsigned int u32x4 __attribute__((ext_vector_type(4)));
typedef unsigned int u32x2 __attribute__((ext_vector_type(2)));
typedef __bf16 bf16x8 __attribute__((ext_vector_type(8)));
typedef unsigned short u16;
typedef unsigned int u32;

static __device__ __forceinline__ u16 f2bf(float f) {
    u32 u = __builtin_bit_cast(u32, f);
    u32 r = u + 0x7fffu + ((u >> 16) & 1u);
    return (u16)(r >> 16);
}
static __device__ __forceinline__ float bf2f(u16 h) {
    u32 u = ((u32)h) << 16;
    return __builtin_bit_cast(float, u);
}

static __device__ __forceinline__ void gload_lds16(const void* g, void* l) {
    __builtin_amdgcn_global_load_lds(
        (const __attribute__((address_space(1))) u32*)g,
        (__attribute__((address_space(3))) u32*)l, 16, 0, 0);
}

static __device__ __forceinline__ bf16x8 ldfrag(const u16* p) {
    return __builtin_bit_cast(bf16x8, *(const u32x4*)p);
}

#define MFMA16(a, b, c) __builtin_amdgcn_mfma_f32_16x16x32_bf16((a), (b), (c), 0, 0, 0)

// ---------------------------------------------------------------------------
// Kernel 1: omega fp32 -> (hi, lo) bf16 split   [R5 verbatim]
// ---------------------------------------------------------------------------
__global__ void k_conv(const float* __restrict__ om, u16* __restrict__ oh,
                       u16* __restrict__ ol) {
    int i = (blockIdx.x * blockDim.x + threadIdx.x) * 4;
    f32x4 x = *(const f32x4*)(om + i);
    ushort4 h, l;
    u16 t;
    t = f2bf(x.x); h.x = t; l.x = f2bf(x.x - bf2f(t));
    t = f2bf(x.y); h.y = t; l.y = f2bf(x.y - bf2f(t));
    t = f2bf(x.z); h.z = t; l.z = f2bf(x.z - bf2f(t));
    t = f2bf(x.w); h.w = t; l.w = f2bf(x.w - bf2f(t));
    *(ushort4*)(oh + i) = h;
    *(ushort4*)(ol + i) = l;
}

// ---------------------------------------------------------------------------
// Kernel 2: merged Stage A (H and W in one grid) — proj = X @ Omega^T with
// split-bf16 (3 MFMA products). Block = 32 rows x all 256 cols -> rowmax
// block-local -> phi (bf16) + em = exp(clamp(-rowmax, +-87)) (f32).
// [R5 verbatim — proven fastest stage A; R6/R7/R8 restructures all regressed]
// ---------------------------------------------------------------------------
__global__ __launch_bounds__(256, 4)
void k_stageA(const float* __restrict__ Hs, const float* __restrict__ Ws,
              const u16* __restrict__ Oh, const u16* __restrict__ Ol,
              u16* __restrict__ phiH, u16* __restrict__ phiW,
              float* __restrict__ emH, float* __restrict__ emW)
{
    __shared__ alignas(16) u16 Ah[32 * 32];
    __shared__ alignas(16) u16 Al[32 * 32];
    __shared__ alignas(16) u16 Bh[256 * 32];
    __shared__ alignas(16) u16 Bl[256 * 32];
    __shared__ float redmax[4][32];

    const int tid  = threadIdx.x;
    const int lane = tid & 63;
    const int wid  = tid >> 6;

    const float* __restrict__ X;
    u16* __restrict__ phi;
    float* __restrict__ em;
    int row0;
    if (blockIdx.x < NN / 32) {
        X = Hs; phi = phiH; em = emH; row0 = blockIdx.x * 32;
    } else {
        X = Ws; phi = phiW; em = emW; row0 = (blockIdx.x - NN / 32) * 32;
    }

    f32x4 acc[2][4];
#pragma unroll
    for (int m = 0; m < 2; ++m)
#pragma unroll
        for (int n = 0; n < 4; ++n) acc[m][n] = f32x4{0.f, 0.f, 0.f, 0.f};

    // A staging: thread loads float4 (row arow, fp32 cols acol..acol+3)
    const int arow = tid >> 3;           // 0..31
    const int acol = (tid & 7) * 4;      // 0,4,..,28
    const float* __restrict__ xrow = X + (long)(row0 + arow) * DD;
    // u16-unit LDS index; XOR swizzle on 8-u16 (16B) blocks
    const int a_idx = arow * 32 + (acol ^ (((arow >> 1) & 3) << 3));

    const int r16 = lane & 15;
    const int h8  = (lane >> 4) << 3;
    int aoffs[2], boffs[4];
#pragma unroll
    for (int m = 0; m < 2; ++m) {
        int row = m * 16 + r16;
        aoffs[m] = row * 32 + (h8 ^ (((row >> 1) & 3) << 3));
    }
#pragma unroll
    for (int n = 0; n < 4; ++n) {
        int row = wid * 64 + n * 16 + r16;
        boffs[n] = row * 32 + (h8 ^ (((row >> 1) & 3) << 3));
    }

    for (int ks = 0; ks < DD / 32; ++ks) {
        const int k0 = ks * 32;
        // Omega tile hi/lo via async global->LDS (width 16), pre-swizzled src
#pragma unroll
        for (int s = 0; s < 4; ++s) {
            const int c    = s * 256 + tid;
            const int brow = c >> 2;
            const int scol = k0 + (((c & 3) << 3) ^ (((brow >> 1) & 3) << 3));
            gload_lds16(Oh + brow * DD + scol, Bh + (s * 256 + wid * 64) * 8);
            gload_lds16(Ol + brow * DD + scol, Bl + (s * 256 + wid * 64) * 8);
        }
        // X tile: load fp32x4, split to hi/lo bf16, write LDS (8B)
        f32x4 x = *(const f32x4*)(xrow + k0 + acol);
        u32x2 ph, pl;
#pragma unroll
        for (int j = 0; j < 2; ++j) {
            u16 h0 = f2bf(x[2 * j]);
            u16 h1 = f2bf(x[2 * j + 1]);
            u16 l0 = f2bf(x[2 * j] - bf2f(h0));
            u16 l1 = f2bf(x[2 * j + 1] - bf2f(h1));
            ph[j] = (u32)h0 | ((u32)h1 << 16);
            pl[j] = (u32)l0 | ((u32)l1 << 16);
        }
        *(u32x2*)(Ah + a_idx) = ph;
        *(u32x2*)(Al + a_idx) = pl;
        __syncthreads();

        bf16x8 fah[2], fal[2], fbh[4], fbl[4];
#pragma unroll
        for (int m = 0; m < 2; ++m) {
            fah[m] = ldfrag(Ah + aoffs[m]);
            fal[m] = ldfrag(Al + aoffs[m]);
        }
#pragma unroll
        for (int n = 0; n < 4; ++n) {
            fbh[n] = ldfrag(Bh + boffs[n]);
            fbl[n] = ldfrag(Bl + boffs[n]);
        }
#pragma unroll
        for (int m = 0; m < 2; ++m)
#pragma unroll
            for (int n = 0; n < 4; ++n) {
                acc[m][n] = MFMA16(fah[m], fbh[n], acc[m][n]);
                acc[m][n] = MFMA16(fah[m], fbl[n], acc[m][n]);
                acc[m][n] = MFMA16(fal[m], fbh[n], acc[m][n]);
            }
        __syncthreads();
    }

    // row max: lane-local over n, then across the 16 lanes sharing a row
#pragma unroll
    for (int m = 0; m < 2; ++m) {
#pragma unroll
        for (int i = 0; i < 4; ++i) {
            float v = fmaxf(fmaxf(acc[m][0][i], acc[m][1][i]),
                            fmaxf(acc[m][2][i], acc[m][3][i]));
            v = fmaxf(v, __shfl_xor(v, 1));
            v = fmaxf(v, __shfl_xor(v, 2));
            v = fmaxf(v, __shfl_xor(v, 4));
            v = fmaxf(v, __shfl_xor(v, 8));
            if (r16 == 0) redmax[wid][m * 16 + ((lane >> 4) << 2) + i] = v;
        }
    }
    __syncthreads();
    if (tid < 32) {
        float fm = fmaxf(fmaxf(redmax[0][tid], redmax[1][tid]),
                         fmaxf(redmax[2][tid], redmax[3][tid]));
        // em = exp(-clamp(max)) so stage B epilogue needs no log/exp
        em[row0 + tid] = __expf(fminf(fmaxf(-fm, -87.f), 87.f));
    }
#pragma unroll
    for (int m = 0; m < 2; ++m) {
#pragma unroll
        for (int i = 0; i < 4; ++i) {
            const int rl = m * 16 + ((lane >> 4) << 2) + i;
            const float fm = fmaxf(fmaxf(redmax[0][rl], redmax[1][rl]),
                                   fmaxf(redmax[2][rl], redmax[3][rl]));
#pragma unroll
            for (int n = 0; n < 4; ++n) {
                float p   = acc[m][n][i];
                float ph_ = (__expf(p - fm) + 1e-6f) * 0.0625f;
                phi[(long)(row0 + rl) * MM + wid * 64 + n * 16 + r16] = f2bf(ph_);
            }
        }
    }
}

// ---------------------------------------------------------------------------
// Kernel 3: Stage B — rf = phi_h @ phi_w^T (K=256), epilogue
//   out = rf' / (rf' + eh*ew),  rf' = rf + 1e-10
// 128x128 tile, 4 waves, BK=64 [K-loop = R9 verbatim].
// Epilogue v2: 2 passes of 64 rows through a 64x130 f32 LDS tile (union
// with As/Bs), synchronized with RAW s_waitcnt(lgkmcnt)+s_barrier only —
// NO vmcnt drains after the K-loop, so all NT stores stay in flight until
// kernel end instead of being acked 4x per block at compiler barriers.
// ---------------------------------------------------------------------------
__global__ __launch_bounds__(256, 3)
void k_stageB(const u16* __restrict__ PH, const u16* __restrict__ PW,
              const float* __restrict__ EH, const float* __restrict__ EW,
              float* __restrict__ out)
{
    // union: K-loop staging (32 KB) | epilogue f32 tile 64x130 (33.28 KB)
    __shared__ alignas(16) unsigned char smem_raw[64 * 130 * 4];
    u16* const As = (u16*)smem_raw;
    u16* const Bs = As + 128 * 64;
    float* const ftile = (float*)smem_raw;
    const int FST = 130;

    const int tid  = threadIdx.x;
    const int lane = tid & 63;
    const int wid  = tid >> 6;
    const int bm   = blockIdx.x >> 6;   // 0..127
    const int bn   = blockIdx.x & 63;   // 0..63
    const int row0 = bm * 128, col0 = bn * 128;
    const int wr   = wid >> 1, wc = wid & 1;
    const int r16  = lane & 15;
    const int h8   = (lane >> 4) << 3;

    f32x4 acc[4][4];
#pragma unroll
    for (int m = 0; m < 4; ++m)
#pragma unroll
        for (int n = 0; n < 4; ++n) acc[m][n] = f32x4{0.f, 0.f, 0.f, 0.f};

    // fragment offsets (u16 units) for both 32-wide k-slices; 128B rows,
    // byte swizzle = ((row&7)<<4)
    int aoffs[2][4], boffs[2][4];
#pragma unroll
    for (int sl = 0; sl < 2; ++sl) {
#pragma unroll
        for (int m = 0; m < 4; ++m) {
            int row = wr * 64 + m * 16 + r16;
            aoffs[sl][m] = row * 64 + (((((sl * 32 + h8) << 1)) ^ ((row & 7) << 4)) >> 1);
        }
#pragma unroll
        for (int n = 0; n < 4; ++n) {
            int row = wc * 64 + n * 16 + r16;
            boffs[sl][n] = row * 64 + (((((sl * 32 + h8) << 1)) ^ ((row & 7) << 4)) >> 1);
        }
    }

    for (int ks = 0; ks < 4; ++ks) {
        const int k0 = ks * 64;
#pragma unroll
        for (int s = 0; s < 4; ++s) {
            const int c    = s * 256 + tid;
            const int row  = c >> 3;
            const int cbl  = ((c & 7) << 4) ^ ((row & 7) << 4);
            const int scol = k0 + (cbl >> 1);
            gload_lds16(PH + (long)(row0 + row) * MM + scol, As + (s * 256 + wid * 64) * 8);
            gload_lds16(PW + (long)(col0 + row) * MM + scol, Bs + (s * 256 + wid * 64) * 8);
        }
        __syncthreads();
#pragma unroll
        for (int sl = 0; sl < 2; ++sl) {
            bf16x8 fa[4], fb[4];
#pragma unroll
            for (int m = 0; m < 4; ++m) fa[m] = ldfrag(As + aoffs[sl][m]);
#pragma unroll
            for (int n = 0; n < 4; ++n) fb[n] = ldfrag(Bs + boffs[sl][n]);
#pragma unroll
            for (int m = 0; m < 4; ++m)
#pragma unroll
                for (int n = 0; n < 4; ++n)
                    acc[m][n] = MFMA16(fa[m], fb[n], acc[m][n]);
        }
        __syncthreads();
    }
    // K-loop's final __syncthreads drained everything: As/Bs reads retired.

    // epilogue: out = rf' / (rf' + eh*ew). 2 passes of 64 rows; LDS-only
    // synchronization (lgkmcnt + raw s_barrier) -> NT stores never drained.
    float ew_[4];
#pragma unroll
    for (int n = 0; n < 4; ++n) ew_[n] = EW[col0 + wc * 64 + n * 16 + r16];

#pragma unroll
    for (int mm = 0; mm < 2; ++mm) {
        if (mm == 1) {
            // WAR: pass-0 ftile ds_reads must retire before overwrite
            asm volatile("s_waitcnt lgkmcnt(0)" ::: "memory");
            __builtin_amdgcn_s_barrier();
        }
#pragma unroll
        for (int ms = 0; ms < 2; ++ms) {
            const int m = 2 * mm + ms;
#pragma unroll
            for (int i = 0; i < 4; ++i) {
                const int lr   = wr * 32 + ms * 16 + ((lane >> 4) << 2) + i; // 0..63
                const int grow = row0 + wr * 64 + m * 16 + ((lane >> 4) << 2) + i;
                const float eh = EH[grow];
#pragma unroll
                for (int n = 0; n < 4; ++n) {
                    float rf = acc[m][n][i] + 1e-10f;
                    float t  = eh * ew_[n];
                    float o  = rf * __builtin_amdgcn_rcpf(rf + t);
                    ftile[lr * FST + wc * 64 + n * 16 + r16] = o;
                }
            }
        }
        // ds_writes visible to all waves (LDS only — no vmcnt drain)
        asm volatile("s_waitcnt lgkmcnt(0)" ::: "memory");
        __builtin_amdgcn_s_barrier();
        // readback + fully-coalesced NT float4 stores (512B / 32 lanes)
#pragma unroll
        for (int p = 0; p < 8; ++p) {
            const int r = p * 8 + (tid >> 5);        // 0..63 local row
            const int c = (tid & 31) * 4;            // 0..124
            f32x4 v = *(const f32x4*)&ftile[r * FST + c];
            // r = wr*32 + ms*16 + q  ->  global row
            const int grow = row0 + (r >> 5) * 64 + (2 * mm + ((r >> 4) & 1)) * 16 + (r & 15);
            __builtin_nontemporal_store(
                v, (f32x4*)(out + (long)grow * KK + col0 + c));
        }
    }
}

// ---------------------------------------------------------------------------
extern "C" void kernel_launch(void* const* d_in, const int* in_sizes, int n_in,
                              void* d_out, int out_size, void* d_ws, size_t ws_size,
                              hipStream_t stream) {
    (void)in_sizes; (void)n_in; (void)out_size; (void)ws_size;
    const float* H  = (const float*)d_in[0];
    const float* W  = (const float*)d_in[1];
    const float* Om = (const float*)d_in[2];
    float* out = (float*)d_out;

    char* ws   = (char*)d_ws;
    u16*  phiH = (u16*)ws;                                       // 8 MB
    u16*  phiW = (u16*)(ws + (size_t)NN * MM * 2);               // 4 MB
    float* emh = (float*)(ws + (size_t)(NN + KK) * MM * 2);      // 64 KB
    float* emw = emh + NN;                                       // 32 KB
    u16*  oh   = (u16*)(emw + KK);                               // 512 KB
    u16*  ol   = oh + MM * DD;                                   // 512 KB

    k_conv<<<(MM * DD) / 1024, 256, 0, stream>>>(Om, oh, ol);
    k_stageA<<<(NN + KK) / 32, 256, 0, stream>>>(H, W, oh, ol, phiH, phiW, emh, emw);
    k_stageB<<<(NN / 128) * (KK / 128), 256, 0, stream>>>(phiH, phiW, emh, emw, out);
}

// Round 11
// 179.544 us; speedup vs baseline: 1.2308x; 1.0097x over previous
//
#include <hip/hip_runtime.h>

#define DD 1024   // hidden size
#define MM 256    // random features
#define NN 16384  // hidden states
#define KK 8192   // weight rows

typedef float f32x4 __attribute__((ext_vector_type(4)));
typedef unsigned int u32x4 __attribute__((ext_vector_type(4)));
typedef unsigned int u32x2 __attribute__((ext_vector_type(2)));
typedef __bf16 bf16x8 __attribute__((ext_vector_type(8)));
typedef unsigned short u16;
typedef unsigned int u32;

static __device__ __forceinline__ u16 f2bf(float f) {
    u32 u = __builtin_bit_cast(u32, f);
    u32 r = u + 0x7fffu + ((u >> 16) & 1u);
    return (u16)(r >> 16);
}
static __device__ __forceinline__ float bf2f(u16 h) {
    u32 u = ((u32)h) << 16;
    return __builtin_bit_cast(float, u);
}

static __device__ __forceinline__ void gload_lds16(const void* g, void* l) {
    __builtin_amdgcn_global_load_lds(
        (const __attribute__((address_space(1))) u32*)g,
        (__attribute__((address_space(3))) u32*)l, 16, 0, 0);
}

static __device__ __forceinline__ bf16x8 ldfrag(const u16* p) {
    return __builtin_bit_cast(bf16x8, *(const u32x4*)p);
}

#define MFMA16(a, b, c) __builtin_amdgcn_mfma_f32_16x16x32_bf16((a), (b), (c), 0, 0, 0)

// ---------------------------------------------------------------------------
// Kernel 1: omega fp32 -> (hi, lo) bf16 split   [R5 verbatim]
// ---------------------------------------------------------------------------
__global__ void k_conv(const float* __restrict__ om, u16* __restrict__ oh,
                       u16* __restrict__ ol) {
    int i = (blockIdx.x * blockDim.x + threadIdx.x) * 4;
    f32x4 x = *(const f32x4*)(om + i);
    ushort4 h, l;
    u16 t;
    t = f2bf(x.x); h.x = t; l.x = f2bf(x.x - bf2f(t));
    t = f2bf(x.y); h.y = t; l.y = f2bf(x.y - bf2f(t));
    t = f2bf(x.z); h.z = t; l.z = f2bf(x.z - bf2f(t));
    t = f2bf(x.w); h.w = t; l.w = f2bf(x.w - bf2f(t));
    *(ushort4*)(oh + i) = h;
    *(ushort4*)(ol + i) = l;
}

// ---------------------------------------------------------------------------
// Kernel 2: merged Stage A (H and W in one grid) — proj = X @ Omega^T with
// split-bf16 (3 MFMA products). Block = 32 rows x all 256 cols -> rowmax
// block-local -> phi (bf16) + em = exp(clamp(-rowmax, +-87)) (f32).
// [R5 verbatim — proven fastest stage A; R6/R7/R8 restructures all regressed]
// ---------------------------------------------------------------------------
__global__ __launch_bounds__(256, 4)
void k_stageA(const float* __restrict__ Hs, const float* __restrict__ Ws,
              const u16* __restrict__ Oh, const u16* __restrict__ Ol,
              u16* __restrict__ phiH, u16* __restrict__ phiW,
              float* __restrict__ emH, float* __restrict__ emW)
{
    __shared__ alignas(16) u16 Ah[32 * 32];
    __shared__ alignas(16) u16 Al[32 * 32];
    __shared__ alignas(16) u16 Bh[256 * 32];
    __shared__ alignas(16) u16 Bl[256 * 32];
    __shared__ float redmax[4][32];

    const int tid  = threadIdx.x;
    const int lane = tid & 63;
    const int wid  = tid >> 6;

    const float* __restrict__ X;
    u16* __restrict__ phi;
    float* __restrict__ em;
    int row0;
    if (blockIdx.x < NN / 32) {
        X = Hs; phi = phiH; em = emH; row0 = blockIdx.x * 32;
    } else {
        X = Ws; phi = phiW; em = emW; row0 = (blockIdx.x - NN / 32) * 32;
    }

    f32x4 acc[2][4];
#pragma unroll
    for (int m = 0; m < 2; ++m)
#pragma unroll
        for (int n = 0; n < 4; ++n) acc[m][n] = f32x4{0.f, 0.f, 0.f, 0.f};

    // A staging: thread loads float4 (row arow, fp32 cols acol..acol+3)
    const int arow = tid >> 3;           // 0..31
    const int acol = (tid & 7) * 4;      // 0,4,..,28
    const float* __restrict__ xrow = X + (long)(row0 + arow) * DD;
    // u16-unit LDS index; XOR swizzle on 8-u16 (16B) blocks
    const int a_idx = arow * 32 + (acol ^ (((arow >> 1) & 3) << 3));

    const int r16 = lane & 15;
    const int h8  = (lane >> 4) << 3;
    int aoffs[2], boffs[4];
#pragma unroll
    for (int m = 0; m < 2; ++m) {
        int row = m * 16 + r16;
        aoffs[m] = row * 32 + (h8 ^ (((row >> 1) & 3) << 3));
    }
#pragma unroll
    for (int n = 0; n < 4; ++n) {
        int row = wid * 64 + n * 16 + r16;
        boffs[n] = row * 32 + (h8 ^ (((row >> 1) & 3) << 3));
    }

    for (int ks = 0; ks < DD / 32; ++ks) {
        const int k0 = ks * 32;
        // Omega tile hi/lo via async global->LDS (width 16), pre-swizzled src
#pragma unroll
        for (int s = 0; s < 4; ++s) {
            const int c    = s * 256 + tid;
            const int brow = c >> 2;
            const int scol = k0 + (((c & 3) << 3) ^ (((brow >> 1) & 3) << 3));
            gload_lds16(Oh + brow * DD + scol, Bh + (s * 256 + wid * 64) * 8);
            gload_lds16(Ol + brow * DD + scol, Bl + (s * 256 + wid * 64) * 8);
        }
        // X tile: load fp32x4, split to hi/lo bf16, write LDS (8B)
        f32x4 x = *(const f32x4*)(xrow + k0 + acol);
        u32x2 ph, pl;
#pragma unroll
        for (int j = 0; j < 2; ++j) {
            u16 h0 = f2bf(x[2 * j]);
            u16 h1 = f2bf(x[2 * j + 1]);
            u16 l0 = f2bf(x[2 * j] - bf2f(h0));
            u16 l1 = f2bf(x[2 * j + 1] - bf2f(h1));
            ph[j] = (u32)h0 | ((u32)h1 << 16);
            pl[j] = (u32)l0 | ((u32)l1 << 16);
        }
        *(u32x2*)(Ah + a_idx) = ph;
        *(u32x2*)(Al + a_idx) = pl;
        __syncthreads();

        bf16x8 fah[2], fal[2], fbh[4], fbl[4];
#pragma unroll
        for (int m = 0; m < 2; ++m) {
            fah[m] = ldfrag(Ah + aoffs[m]);
            fal[m] = ldfrag(Al + aoffs[m]);
        }
#pragma unroll
        for (int n = 0; n < 4; ++n) {
            fbh[n] = ldfrag(Bh + boffs[n]);
            fbl[n] = ldfrag(Bl + boffs[n]);
        }
#pragma unroll
        for (int m = 0; m < 2; ++m)
#pragma unroll
            for (int n = 0; n < 4; ++n) {
                acc[m][n] = MFMA16(fah[m], fbh[n], acc[m][n]);
                acc[m][n] = MFMA16(fah[m], fbl[n], acc[m][n]);
                acc[m][n] = MFMA16(fal[m], fbh[n], acc[m][n]);
            }
        __syncthreads();
    }

    // row max: lane-local over n, then across the 16 lanes sharing a row
#pragma unroll
    for (int m = 0; m < 2; ++m) {
#pragma unroll
        for (int i = 0; i < 4; ++i) {
            float v = fmaxf(fmaxf(acc[m][0][i], acc[m][1][i]),
                            fmaxf(acc[m][2][i], acc[m][3][i]));
            v = fmaxf(v, __shfl_xor(v, 1));
            v = fmaxf(v, __shfl_xor(v, 2));
            v = fmaxf(v, __shfl_xor(v, 4));
            v = fmaxf(v, __shfl_xor(v, 8));
            if (r16 == 0) redmax[wid][m * 16 + ((lane >> 4) << 2) + i] = v;
        }
    }
    __syncthreads();
    if (tid < 32) {
        float fm = fmaxf(fmaxf(redmax[0][tid], redmax[1][tid]),
                         fmaxf(redmax[2][tid], redmax[3][tid]));
        // em = exp(-clamp(max)) so stage B epilogue needs no log/exp
        em[row0 + tid] = __expf(fminf(fmaxf(-fm, -87.f), 87.f));
    }
#pragma unroll
    for (int m = 0; m < 2; ++m) {
#pragma unroll
        for (int i = 0; i < 4; ++i) {
            const int rl = m * 16 + ((lane >> 4) << 2) + i;
            const float fm = fmaxf(fmaxf(redmax[0][rl], redmax[1][rl]),
                                   fmaxf(redmax[2][rl], redmax[3][rl]));
#pragma unroll
            for (int n = 0; n < 4; ++n) {
                float p   = acc[m][n][i];
                float ph_ = (__expf(p - fm) + 1e-6f) * 0.0625f;
                phi[(long)(row0 + rl) * MM + wid * 64 + n * 16 + r16] = f2bf(ph_);
            }
        }
    }
}

// ---------------------------------------------------------------------------
// Kernel 3: Stage B — rf = phi_h @ phi_w^T (K=256), epilogue
//   out = rf' / (rf' + eh*ew),  rf' = rf + 1e-10
// [R10 verbatim EXCEPT __launch_bounds__(256,4): LDS union is 33.3 KB so
// 4 blocks/CU fit (133 KB < 160 KB); R10's (256,3) was the only cap.
// +33% waves/SIMD to decohere the phase-locked fetch/store bursts.]
// ---------------------------------------------------------------------------
__global__ __launch_bounds__(256, 4)
void k_stageB(const u16* __restrict__ PH, const u16* __restrict__ PW,
              const float* __restrict__ EH, const float* __restrict__ EW,
              float* __restrict__ out)
{
    // union: K-loop staging (32 KB) | epilogue f32 tile 64x130 (33.28 KB)
    __shared__ alignas(16) unsigned char smem_raw[64 * 130 * 4];
    u16* const As = (u16*)smem_raw;
    u16* const Bs = As + 128 * 64;
    float* const ftile = (float*)smem_raw;
    const int FST = 130;

    const int tid  = threadIdx.x;
    const int lane = tid & 63;
    const int wid  = tid >> 6;
    const int bm   = blockIdx.x >> 6;   // 0..127
    const int bn   = blockIdx.x & 63;   // 0..63
    const int row0 = bm * 128, col0 = bn * 128;
    const int wr   = wid >> 1, wc = wid & 1;
    const int r16  = lane & 15;
    const int h8   = (lane >> 4) << 3;

    f32x4 acc[4][4];
#pragma unroll
    for (int m = 0; m < 4; ++m)
#pragma unroll
        for (int n = 0; n < 4; ++n) acc[m][n] = f32x4{0.f, 0.f, 0.f, 0.f};

    // fragment offsets (u16 units) for both 32-wide k-slices; 128B rows,
    // byte swizzle = ((row&7)<<4)
    int aoffs[2][4], boffs[2][4];
#pragma unroll
    for (int sl = 0; sl < 2; ++sl) {
#pragma unroll
        for (int m = 0; m < 4; ++m) {
            int row = wr * 64 + m * 16 + r16;
            aoffs[sl][m] = row * 64 + (((((sl * 32 + h8) << 1)) ^ ((row & 7) << 4)) >> 1);
        }
#pragma unroll
        for (int n = 0; n < 4; ++n) {
            int row = wc * 64 + n * 16 + r16;
            boffs[sl][n] = row * 64 + (((((sl * 32 + h8) << 1)) ^ ((row & 7) << 4)) >> 1);
        }
    }

    for (int ks = 0; ks < 4; ++ks) {
        const int k0 = ks * 64;
#pragma unroll
        for (int s = 0; s < 4; ++s) {
            const int c    = s * 256 + tid;
            const int row  = c >> 3;
            const int cbl  = ((c & 7) << 4) ^ ((row & 7) << 4);
            const int scol = k0 + (cbl >> 1);
            gload_lds16(PH + (long)(row0 + row) * MM + scol, As + (s * 256 + wid * 64) * 8);
            gload_lds16(PW + (long)(col0 + row) * MM + scol, Bs + (s * 256 + wid * 64) * 8);
        }
        __syncthreads();
#pragma unroll
        for (int sl = 0; sl < 2; ++sl) {
            bf16x8 fa[4], fb[4];
#pragma unroll
            for (int m = 0; m < 4; ++m) fa[m] = ldfrag(As + aoffs[sl][m]);
#pragma unroll
            for (int n = 0; n < 4; ++n) fb[n] = ldfrag(Bs + boffs[sl][n]);
#pragma unroll
            for (int m = 0; m < 4; ++m)
#pragma unroll
                for (int n = 0; n < 4; ++n)
                    acc[m][n] = MFMA16(fa[m], fb[n], acc[m][n]);
        }
        __syncthreads();
    }
    // K-loop's final __syncthreads drained everything: As/Bs reads retired.

    // epilogue: out = rf' / (rf' + eh*ew). 2 passes of 64 rows; LDS-only
    // synchronization (lgkmcnt + raw s_barrier) -> NT stores never drained.
    float ew_[4];
#pragma unroll
    for (int n = 0; n < 4; ++n) ew_[n] = EW[col0 + wc * 64 + n * 16 + r16];

#pragma unroll
    for (int mm = 0; mm < 2; ++mm) {
        if (mm == 1) {
            // WAR: pass-0 ftile ds_reads must retire before overwrite
            asm volatile("s_waitcnt lgkmcnt(0)" ::: "memory");
            __builtin_amdgcn_s_barrier();
        }
#pragma unroll
        for (int ms = 0; ms < 2; ++ms) {
            const int m = 2 * mm + ms;
#pragma unroll
            for (int i = 0; i < 4; ++i) {
                const int lr   = wr * 32 + ms * 16 + ((lane >> 4) << 2) + i; // 0..63
                const int grow = row0 + wr * 64 + m * 16 + ((lane >> 4) << 2) + i;
                const float eh = EH[grow];
#pragma unroll
                for (int n = 0; n < 4; ++n) {
                    float rf = acc[m][n][i] + 1e-10f;
                    float t  = eh * ew_[n];
                    float o  = rf * __builtin_amdgcn_rcpf(rf + t);
                    ftile[lr * FST + wc * 64 + n * 16 + r16] = o;
                }
            }
        }
        // ds_writes visible to all waves (LDS only — no vmcnt drain)
        asm volatile("s_waitcnt lgkmcnt(0)" ::: "memory");
        __builtin_amdgcn_s_barrier();
        // readback + fully-coalesced NT float4 stores (512B / 32 lanes)
#pragma unroll
        for (int p = 0; p < 8; ++p) {
            const int r = p * 8 + (tid >> 5);        // 0..63 local row
            const int c = (tid & 31) * 4;            // 0..124
            f32x4 v = *(const f32x4*)&ftile[r * FST + c];
            // r = wr*32 + ms*16 + q  ->  global row
            const int grow = row0 + (r >> 5) * 64 + (2 * mm + ((r >> 4) & 1)) * 16 + (r & 15);
            __builtin_nontemporal_store(
                v, (f32x4*)(out + (long)grow * KK + col0 + c));
        }
    }
}

// ---------------------------------------------------------------------------
extern "C" void kernel_launch(void* const* d_in, const int* in_sizes, int n_in,
                              void* d_out, int out_size, void* d_ws, size_t ws_size,
                              hipStream_t stream) {
    (void)in_sizes; (void)n_in; (void)out_size; (void)ws_size;
    const float* H  = (const float*)d_in[0];
    const float* W  = (const float*)d_in[1];
    const float* Om = (const float*)d_in[2];
    float* out = (float*)d_out;

    char* ws   = (char*)d_ws;
    u16*  phiH = (u16*)ws;                                       // 8 MB
    u16*  phiW = (u16*)(ws + (size_t)NN * MM * 2);               // 4 MB
    float* emh = (float*)(ws + (size_t)(NN + KK) * MM * 2);      // 64 KB
    float* emw = emh + NN;                                       // 32 KB
    u16*  oh   = (u16*)(emw + KK);                               // 512 KB
    u16*  ol   = oh + MM * DD;                                   // 512 KB

    k_conv<<<(MM * DD) / 1024, 256, 0, stream>>>(Om, oh, ol);
    k_stageA<<<(NN + KK) / 32, 256, 0, stream>>>(H, W, oh, ol, phiH, phiW, emh, emw);
    k_stageB<<<(NN / 128) * (KK / 128), 256, 0, stream>>>(phiH, phiW, emh, emw, out);
}